// Round 3
// baseline (829.352 us; speedup 1.0000x reference)
//
#include <hip/hip_runtime.h>
#include <hip/hip_bf16.h>

// PointCloudNetPersistencePrediction — round 22: revert R21 (W-materialization
// lost: 134MB W streamed at HBM rate ~25us/apply vs ~16.7us recompute; LLC
// does not retain a 134MB streaming buffer). Back to R20 eval-in-registers,
// restructured: block = 256 thr = 4 waves sharing ONE 16-row m-tile, waves
// own k-QUARTERS (512k, 16 kc each). Grid (128,16)=2048 blocks = 8/CU x 4
// waves = 32 waves/CU (full occupancy kept — minimal k-split that still
// fills the chip). Removes: Xp LDS staging + pre-barrier (j-entries read
// direct from L2-resident Xp, 16-lane-broadcast pattern), 8->4-way cross-
// wave reduction (one barrier total), separate deg pass (deg = col-3 of the
// same partial sums). Numerics: identical eval + MFMA; only k-grouping
// changes (8x256 -> 4x512), ~1e-7 f32 perturbation under f16 chain quantum.

#define NN 2048
#define NPAIR 16

typedef _Float16 half8 __attribute__((ext_vector_type(8)));
typedef _Float16 f16x2 __attribute__((ext_vector_type(2)));
typedef float f32x4 __attribute__((ext_vector_type(4)));

extern "C" __device__ f16x2 __ocml_exp2_2f16(f16x2);   // packed v_exp_f16

#define C2F 0.28853900817779268f   //  0.2 * log2(e)
#define CWF -0.14426950408889634f  // -0.1 * log2(e)
#define NL2T 3.3219280948873623f   // -log2(0.1); qi' = qi + NL2T

// ---- init+pack fused: Xs fp32 [p][i][{x,y,z,q}]; XT fp16 [p][16][2048]
//      (row3 = ones -> deg via MFMA); Xp packed fp16 j-pair entries ----
__global__ __launch_bounds__(256) void initpack_k(const float* __restrict__ pc,
                                                  const float* __restrict__ alphas,
                                                  float* __restrict__ Xs,
                                                  _Float16* __restrict__ XT,
                                                  _Float16* __restrict__ Xp) {
    int gid = blockIdx.x * 256 + threadIdx.x;
    if (gid >= NPAIR * NN) return;
    int p = gid >> 11, i = gid & (NN - 1);
    int b = p >> 2, k = p & 3;
    const float* pcr = pc + ((size_t)b * NN + i) * 3;
    const float* al  = alphas + k * 3;
    float x = pcr[0] * al[0], y = pcr[1] * al[1], z = pcr[2] * al[2];
    float q = CWF * (x * x + y * y + z * z);
    float4 o; o.x = x; o.y = y; o.z = z; o.w = q;
    ((float4*)Xs)[gid] = o;
    _Float16* xt = XT + (size_t)p * 16 * NN + i;
    xt[0 * NN] = (_Float16)x;
    xt[1 * NN] = (_Float16)y;
    xt[2 * NN] = (_Float16)z;
    xt[3 * NN] = (_Float16)1.0f;
#pragma unroll
    for (int n = 4; n < 16; ++n) xt[n * NN] = (_Float16)0.f;
    _Float16* xp = Xp + ((size_t)p * 1024 + (i >> 1)) * 8 + (i & 1);
    xp[0] = (_Float16)x; xp[2] = (_Float16)y;
    xp[4] = (_Float16)z; xp[6] = (_Float16)q;
}

// ---- fused apply: out = f16(0.5*cur + ihd (x) (W@cur^T)^T).
// 256 thr = 4 waves on one 16-row m-tile, k-quarters (16 kc of K=32).
// j-pair entries read direct from global Xp (L2-hot, lane-broadcast).
// Epilogue: 4-partial LDS reduce, one barrier; deg = col 3 (ones row).
// BUILDU: step-8 epilogue emits U into rows 4-15 of out (combined bank).
template<bool FIRST, bool BUILDU>
__global__ __launch_bounds__(256, 8)
void apply_k(const float* __restrict__ Xs, const _Float16* __restrict__ Xp,
             float* __restrict__ ihd,
             const _Float16* __restrict__ cur, _Float16* __restrict__ out,
             float* __restrict__ lvl, int t,
             const float* __restrict__ LT1u) {
    __shared__ __align__(16) float smem[1088];     // 4x256 partials + 48 stash
    const int tid  = threadIdx.x;
    const int lane = tid & 63;
    const int wv   = tid >> 6;                     // k-quarter 0..3
    const int p    = blockIdx.y;
    const int m0   = blockIdx.x * 16;
    const int idx16 = lane & 15, quad = lane >> 4;

    // per-row (m) constants for the A-operand rows m0+idx16
    f16x2 qi2, xx2, xy2, xz2;
    {
        float4 v = *(const float4*)(Xs + ((size_t)p * NN + m0 + idx16) * 4);
        _Float16 q = (_Float16)(v.w + NL2T);
        _Float16 x = (_Float16)(C2F * v.x);
        _Float16 y = (_Float16)(C2F * v.y);
        _Float16 z = (_Float16)(C2F * v.z);
        qi2 = (f16x2){q, q}; xx2 = (f16x2){x, x};
        xy2 = (f16x2){y, y}; xz2 = (f16x2){z, z};
    }
    const f16x2 SC2 = (f16x2){(_Float16)32768.f, (_Float16)32768.f};

    const _Float16* bp = cur + ((size_t)p * 16 + idx16) * NN + wv * 512 + quad * 8;
    const float4* Xpp = (const float4*)(Xp + (size_t)p * 8192);  // 1024 j-pair entries
    f32x4 acc = {0.f, 0.f, 0.f, 0.f};

    for (int kc = 0; kc < 16; ++kc) {
        const int pb = wv * 256 + kc * 16 + quad * 4;  // j-pair entry base
        half8 bf = *(const half8*)(bp + kc * 32);
        union { f16x2 h2[4]; half8 h8; } af;
#pragma unroll
        for (int jp = 0; jp < 4; ++jp) {
            union { float4 f; f16x2 h[4]; } e;
            e.f = Xpp[pb + jp];                    // {x2,y2,z2,q2} for 2 j
            f16x2 tv = qi2 + e.h[3];
            tv = __builtin_elementwise_fma(xx2, e.h[0], tv);
            tv = __builtin_elementwise_fma(xy2, e.h[1], tv);
            tv = __builtin_elementwise_fma(xz2, e.h[2], tv);
            // threshold folded into exp arg: t'<0 -> arg<=-24 -> exp2 = 0
            f16x2 u = __builtin_elementwise_min(tv, tv * SC2);
            af.h2[jp] = __ocml_exp2_2f16(u);       // = 10*w (2^3.32 fold)
        }
        acc = __builtin_amdgcn_mfma_f32_16x16x32_f16(af.h8, bf, acc, 0, 0, 0);
    }

    // ---- epilogue: 4 k-partials in LDS, single reduce pass ----
    *(f32x4*)&smem[wv * 256 + lane * 4] = acc;
    __syncthreads();

    // thread (n = tid>>4, rr = tid&15) owns output element (row m0+rr, col n)
    const int n  = tid >> 4;
    const int rr = tid & 15;
    const int row = m0 + rr;
    const int base = (rr >> 2) * 64 + (rr & 3);    // C-layout flat index (w/o col)

    float sum = 0.f;                               // = 10*(W@B)[row][n]
#pragma unroll
    for (int g = 0; g < 4; ++g) sum += smem[g * 256 + base + n * 4];
    float ihEff;
    if (FIRST) {
        float deg10 = 0.f;                         // = 10*deg (col 3 = ones row)
#pragma unroll
        for (int g = 0; g < 4; ++g) deg10 += smem[g * 256 + base + 12];
        float ih = 5.0f / deg10;                   // = 0.5/deg
        if (n == 3) ihd[p * NN + row] = ih;
        ihEff = 0.1f * ih;
    } else {
        ihEff = 0.1f * ihd[p * NN + row];
    }
    float cv = (float)cur[((size_t)p * 16 + n) * NN + row];
    float o1v = 0.5f * cv + ihEff * sum;
    if (lvl) lvl[(((size_t)p * 5 + t) * 16 + n) * NN + row] = o1v;

    if (!BUILDU) {
        out[((size_t)p * 16 + n) * NN + row] = (_Float16)o1v;
    } else {
        // stash fresh t=8 (rows 0-2), then overwrite rows 4-15 with U
        if (n < 3) smem[1024 + n * 16 + rr] = o1v;
        __syncthreads();
        float oval = o1v;                          // rows 0-3: t=8 state
        if (n >= 4) {                              // rows 4-15: U = |psi_jw|_c
            const int u = n - 4, jw = u / 3, c = u - 3 * jw;
            float a = (jw == 0) ? Xs[((size_t)p * NN + row) * 4 + c]
                                : LT1u[(((size_t)p * 5 + (jw - 1)) * 16 + c) * NN + row];
            float bb = (jw == 3) ? smem[1024 + c * 16 + rr]
                                 : LT1u[(((size_t)p * 5 + jw) * 16 + c) * NN + row];
            oval = fabsf(a - bb);
        }
        out[((size_t)p * 16 + n) * NN + row] = (_Float16)oval;
    }
}

// ---- final mean over N of 48 features ----
// LT1 slots 0-3: bank1 t=1,2,4,8 (rows 0-2 live).
// LT2 slots 0-4: combined t=1,2,4,8,16 of the U-chain (rows 4-15), with
// slot 3 rows 0-2 additionally = bank1 t=16 (low-pass).
__global__ __launch_bounds__(64) void reduce_k(const float* __restrict__ Xs,
                                               const float* __restrict__ LT1,
                                               const float* __restrict__ LT2,
                                               float* __restrict__ out) {
    int f = blockIdx.x, p = blockIdx.y, lane = threadIdx.x;
    const float* l1 = LT1 + (size_t)p * 5 * 16 * NN;
    const float* l2 = LT2 + (size_t)p * 5 * 16 * NN;
    float s = 0.f;
    for (int m = lane; m < NN; m += 64) {
        float v;
        if (f < 3) {
            v = l2[((size_t)3 * 16 + f) * NN + m];            // P^16 F
        } else if (f < 18) {
            int j = (f - 3) / 3, c = (f - 3) % 3;
            float a = (j == 0) ? Xs[((size_t)p * NN + m) * 4 + c]
                               : l1[((size_t)(j - 1) * 16 + c) * NN + m];
            float b = (j < 4) ? l1[((size_t)j * 16 + c) * NN + m]
                              : l2[((size_t)3 * 16 + c) * NN + m];  // t16
            v = fabsf(a - b);
        } else {
            int gg = f - 18, j2, uc;
            if (gg < 3)       { j2 = 1; uc = gg; }
            else if (gg < 9)  { j2 = 2; uc = gg - 3; }
            else if (gg < 18) { j2 = 3; uc = gg - 9; }
            else              { j2 = 4; uc = gg - 18; }
            v = fabsf(l2[((size_t)(j2 - 1) * 16 + uc + 4) * NN + m]
                    - l2[((size_t)j2 * 16 + uc + 4) * NN + m]);
        }
        s += v;
    }
#pragma unroll
    for (int off = 32; off > 0; off >>= 1) s += __shfl_down(s, off, 64);
    if (lane == 0) out[p * 48 + f] = s * (1.0f / NN);
}

extern "C" void kernel_launch(void* const* d_in, const int* in_sizes, int n_in,
                              void* d_out, int out_size, void* d_ws, size_t ws_size,
                              hipStream_t stream) {
    const float* pc     = (const float*)d_in[0];
    const float* alphas = (const float*)d_in[1];
    float* outp = (float*)d_out;

    char* base = (char*)d_ws;
    size_t off = 0;
    auto carve = [&](size_t bytes) -> void* {
        void* r = base + off;
        off = (off + bytes + 255) & ~(size_t)255;
        return r;
    };
    float*     Xs  = (float*)carve((size_t)NPAIR * NN * 4 * sizeof(float));
    _Float16*  Xp  = (_Float16*)carve((size_t)NPAIR * 1024 * 8 * 2);
    float*     ihd = (float*)carve((size_t)NPAIR * NN * sizeof(float));
    _Float16*  XT  = (_Float16*)carve((size_t)NPAIR * 16 * NN * 2);
    _Float16*  pA  = (_Float16*)carve((size_t)NPAIR * 16 * NN * 2);
    _Float16*  pB  = (_Float16*)carve((size_t)NPAIR * 16 * NN * 2);
    float*     LT1 = (float*)carve((size_t)NPAIR * 5 * 16 * NN * sizeof(float));
    float*     LT2 = (float*)carve((size_t)NPAIR * 5 * 16 * NN * sizeof(float));

    dim3 gridA(NN / 16, NPAIR);   // 128 x 16 = 2048 blocks, 8/CU

    initpack_k<<<dim3((NPAIR * NN) / 256), 256, 0, stream>>>(pc, alphas, Xs, XT, Xp);

    // phase 1: bank1 steps 1..8 (t=1,2,4,8 -> LT1 slots 0..3); step 8 also
    // packs U into rows 4-15 of its output (combined bank).
    const _Float16* c1 = XT;
    int slot = 0;
    for (int step = 1; step <= 8; ++step) {
        _Float16* o1 = (c1 == pA) ? pB : pA;
        bool sv = (step & (step - 1)) == 0;
        float* lv = sv ? LT1 : nullptr;
        if (step == 1)
            apply_k<true, false><<<gridA, 256, 0, stream>>>(Xs, Xp, ihd,
                c1, o1, lv, slot, nullptr);
        else if (step == 8)
            apply_k<false, true><<<gridA, 256, 0, stream>>>(Xs, Xp, ihd,
                c1, o1, lv, slot, LT1);
        else
            apply_k<false, false><<<gridA, 256, 0, stream>>>(Xs, Xp, ihd,
                c1, o1, lv, slot, nullptr);
        if (sv) ++slot;
        c1 = o1;
    }

    // phase 2: combined bank, 16 uniform steps.
    // saves at i = 1,2,4,8,16 -> LT2 slots 0..4 (slot 3 rows 0-2 double as
    // bank1 t=16 low-pass; rows 4-15 are the diffused-U chain).
    int slot2 = 0;
    for (int i = 1; i <= 16; ++i) {
        _Float16* o1 = (c1 == pA) ? pB : pA;
        bool sv = (i & (i - 1)) == 0;
        float* lv = sv ? LT2 : nullptr;
        apply_k<false, false><<<gridA, 256, 0, stream>>>(Xs, Xp, ihd,
            c1, o1, lv, slot2, nullptr);
        if (sv) ++slot2;
        c1 = o1;
    }

    reduce_k<<<dim3(48, NPAIR), 64, 0, stream>>>(Xs, LT1, LT2, outp);
}

// Round 4
// 436.747 us; speedup vs baseline: 1.8989x; 1.8989x over previous
//
#include <hip/hip_runtime.h>
#include <hip/hip_bf16.h>

// PointCloudNetPersistencePrediction — round 23: revert R22 (global Xp reads
// in the eval inner loop = exposed vmem latency, −91%; eval operands must be
// LDS/register — same lesson as R21's W-streaming failure). Base = R20
// (434.8us) with two barrier eliminations, inner loop untouched:
// (1) per-wave Xp slice staging: wave wv only ever reads entries
//     [wv*128, wv*128+128) (pb = wv*128 + kc*16 + quad*4 + jp, kc<8), so
//     each wave stages its own 2KB slice -> NO start __syncthreads, no
//     8-wave convoy at kernel entry.
// (2) MFMA partials go to a dedicated LDS region (smem[4096..8191]) instead
//     of overwriting the Xp region -> no pre-partial barrier. One
//     __syncthreads total (partials -> cross-wave reduce). 32.4KB LDS x 4
//     blocks/CU = 130KB < 160KB, 32 waves/CU kept.
// Numerics bit-identical to R20 (same k-grouping, same MFMA order).

#define NN 2048
#define NPAIR 16

typedef _Float16 half8 __attribute__((ext_vector_type(8)));
typedef _Float16 f16x2 __attribute__((ext_vector_type(2)));
typedef float f32x4 __attribute__((ext_vector_type(4)));

extern "C" __device__ f16x2 __ocml_exp2_2f16(f16x2);   // packed v_exp_f16

#define C2F 0.28853900817779268f   //  0.2 * log2(e)
#define CWF -0.14426950408889634f  // -0.1 * log2(e)
#define NL2T 3.3219280948873623f   // -log2(0.1); qi' = qi + NL2T

// ---- init+pack fused: Xs fp32 [p][i][{x,y,z,q}]; XT fp16 [p][16][2048]
//      (row3 = ones -> deg via MFMA); Xp packed fp16 j-pair entries ----
__global__ __launch_bounds__(256) void initpack_k(const float* __restrict__ pc,
                                                  const float* __restrict__ alphas,
                                                  float* __restrict__ Xs,
                                                  _Float16* __restrict__ XT,
                                                  _Float16* __restrict__ Xp) {
    int gid = blockIdx.x * 256 + threadIdx.x;
    if (gid >= NPAIR * NN) return;
    int p = gid >> 11, i = gid & (NN - 1);
    int b = p >> 2, k = p & 3;
    const float* pcr = pc + ((size_t)b * NN + i) * 3;
    const float* al  = alphas + k * 3;
    float x = pcr[0] * al[0], y = pcr[1] * al[1], z = pcr[2] * al[2];
    float q = CWF * (x * x + y * y + z * z);
    float4 o; o.x = x; o.y = y; o.z = z; o.w = q;
    ((float4*)Xs)[gid] = o;
    _Float16* xt = XT + (size_t)p * 16 * NN + i;
    xt[0 * NN] = (_Float16)x;
    xt[1 * NN] = (_Float16)y;
    xt[2 * NN] = (_Float16)z;
    xt[3 * NN] = (_Float16)1.0f;
#pragma unroll
    for (int n = 4; n < 16; ++n) xt[n * NN] = (_Float16)0.f;
    _Float16* xp = Xp + ((size_t)p * 1024 + (i >> 1)) * 8 + (i & 1);
    xp[0] = (_Float16)x; xp[2] = (_Float16)y;
    xp[4] = (_Float16)z; xp[6] = (_Float16)q;
}

// ---- fused apply: out = f16(0.5*cur + ihd (x) (W@cur^T)^T).
// 512 thr = 8 K-waves (chunk 256); lane: s=2 m-subtiles; M=32; grid (64,16).
// BUILDU: step-8 epilogue emits U into rows 4-15 of out (combined bank);
// t=8 cols 0-2 stashed via 96-float LDS for the jw=3 wavelet.
template<bool FIRST, bool BUILDU>
__global__ __launch_bounds__(512, 8)
void apply_k(const float* __restrict__ Xs, const _Float16* __restrict__ Xp,
             float* __restrict__ ihd,
             const _Float16* __restrict__ cur, _Float16* __restrict__ out,
             float* __restrict__ lvl, int t,
             const float* __restrict__ LT1u) {
    // [0..4095]   : staged Xp (1024 float4 entries)
    // [4096..8191]: 8 waves x 512 MFMA partials
    // [8192..8287]: BUILDU stash (3 cols x 32 rows)
    __shared__ __align__(16) float smem[8288];
    const int tid  = threadIdx.x;
    const int lane = tid & 63;
    const int wv   = tid >> 6;                     // K-group 0..7
    const int p    = blockIdx.y;
    const int m0   = blockIdx.x * 32;
    const int idx16 = lane & 15, quad = lane >> 4;

    {
        // per-wave slice staging: wave wv reads only entries
        // [wv*128, wv*128+128) in the k-loop -> stage own slice, NO barrier.
        const float4* src = (const float4*)(Xp + (size_t)p * 8192);
        float4* dst = (float4*)smem;
        dst[wv * 128 + lane]      = src[wv * 128 + lane];
        dst[wv * 128 + 64 + lane] = src[wv * 128 + 64 + lane];
    }

    f16x2 qi2[2], xx2[2], xy2[2], xz2[2];
#pragma unroll
    for (int s = 0; s < 2; ++s) {
        float4 v = *(const float4*)(Xs + ((size_t)p * NN + m0 + s * 16 + idx16) * 4);
        _Float16 q = (_Float16)(v.w + NL2T);
        _Float16 x = (_Float16)(C2F * v.x);
        _Float16 y = (_Float16)(C2F * v.y);
        _Float16 z = (_Float16)(C2F * v.z);
        qi2[s] = (f16x2){q, q}; xx2[s] = (f16x2){x, x};
        xy2[s] = (f16x2){y, y}; xz2[s] = (f16x2){z, z};
    }
    const f16x2 SC2 = (f16x2){(_Float16)32768.f, (_Float16)32768.f};

    const _Float16* bp = cur + ((size_t)p * 16 + idx16) * NN + wv * 256 + quad * 8;
    f32x4 acc[2] = {{0.f,0.f,0.f,0.f},{0.f,0.f,0.f,0.f}};

    for (int kc = 0; kc < 8; ++kc) {
        const int pb = wv * 128 + kc * 16 + quad * 4;  // j-pair entry base
        half8 bf = *(const half8*)(bp + kc * 32);
        union { f16x2 h2[4]; half8 h8; } af[2];
#pragma unroll
        for (int jp = 0; jp < 4; ++jp) {
            union { float4 f; f16x2 h[4]; } e;
            e.f = ((const float4*)smem)[pb + jp];      // {x2,y2,z2,q2} for 2 j
#pragma unroll
            for (int s = 0; s < 2; ++s) {
                f16x2 tv = qi2[s] + e.h[3];
                tv = __builtin_elementwise_fma(xx2[s], e.h[0], tv);
                tv = __builtin_elementwise_fma(xy2[s], e.h[1], tv);
                tv = __builtin_elementwise_fma(xz2[s], e.h[2], tv);
                // threshold folded into exp arg: t'<0 -> arg<=-24 -> exp2 = 0
                f16x2 u = __builtin_elementwise_min(tv, tv * SC2);
                af[s].h2[jp] = __ocml_exp2_2f16(u);    // = 10*w (2^3.32 fold)
            }
        }
#pragma unroll
        for (int s = 0; s < 2; ++s)
            acc[s] = __builtin_amdgcn_mfma_f32_16x16x32_f16(af[s].h8, bf, acc[s], 0, 0, 0);
    }

    // ---- epilogue (coalesced mapping: n = tid>>5, row = m0 + (tid&31)) ----
    const int n  = tid >> 5;                        // output row of [16][NN]
    const int rr = tid & 31;                        // row within m-block
    const int s2 = rr >> 4, mloc = rr & 15;
    const int base = s2 * 256 + (mloc >> 2) * 64 + (mloc & 3);
    const int row = m0 + rr;
    float ihEff;
    if (!FIRST) ihEff = 0.1f * ihd[p * NN + row];

    // partials to dedicated region -> no pre-barrier needed
#pragma unroll
    for (int s = 0; s < 2; ++s)
        *(f32x4*)&smem[4096 + wv * 512 + s * 256 + lane * 4] = acc[s];
    __syncthreads();

    float sum = 0.f;                               // = 10*(W@B)
#pragma unroll
    for (int g = 0; g < 8; ++g) sum += smem[4096 + g * 512 + base + n * 4];
    if (FIRST) {
        float deg10 = 0.f;                         // = 10*deg (col 3 = ones)
#pragma unroll
        for (int g = 0; g < 8; ++g) deg10 += smem[4096 + g * 512 + base + 12];
        float ih = 5.0f / deg10;                   // = 0.5/deg
        if (n == 3) ihd[p * NN + row] = ih;
        ihEff = 0.1f * ih;
    }
    float cv = (float)cur[((size_t)p * 16 + n) * NN + row];
    float o1v = 0.5f * cv + ihEff * sum;
    if (lvl) lvl[(((size_t)p * 5 + t) * 16 + n) * NN + row] = o1v;

    if (!BUILDU) {
        out[((size_t)p * 16 + n) * NN + row] = (_Float16)o1v;
    } else {
        // stash fresh t=8 (rows 0-2), then overwrite rows 4-15 with U
        if (n < 3) smem[8192 + n * 32 + rr] = o1v;
        __syncthreads();
        float oval = o1v;                          // rows 0-3: t=8 state
        if (n >= 4) {                              // rows 4-15: U = |psi_jw|_c
            const int u = n - 4, jw = u / 3, c = u - 3 * jw;
            float a = (jw == 0) ? Xs[((size_t)p * NN + row) * 4 + c]
                                : LT1u[(((size_t)p * 5 + (jw - 1)) * 16 + c) * NN + row];
            float bb = (jw == 3) ? smem[8192 + c * 32 + rr]
                                 : LT1u[(((size_t)p * 5 + jw) * 16 + c) * NN + row];
            oval = fabsf(a - bb);
        }
        out[((size_t)p * 16 + n) * NN + row] = (_Float16)oval;
    }
}

// ---- final mean over N of 48 features ----
// LT1 slots 0-3: bank1 t=1,2,4,8 (rows 0-2 live).
// LT2 slots 0-4: combined t=1,2,4,8,16 of the U-chain (rows 4-15), with
// slot 3 rows 0-2 additionally = bank1 t=16 (low-pass).
__global__ __launch_bounds__(64) void reduce_k(const float* __restrict__ Xs,
                                               const float* __restrict__ LT1,
                                               const float* __restrict__ LT2,
                                               float* __restrict__ out) {
    int f = blockIdx.x, p = blockIdx.y, lane = threadIdx.x;
    const float* l1 = LT1 + (size_t)p * 5 * 16 * NN;
    const float* l2 = LT2 + (size_t)p * 5 * 16 * NN;
    float s = 0.f;
    for (int m = lane; m < NN; m += 64) {
        float v;
        if (f < 3) {
            v = l2[((size_t)3 * 16 + f) * NN + m];            // P^16 F
        } else if (f < 18) {
            int j = (f - 3) / 3, c = (f - 3) % 3;
            float a = (j == 0) ? Xs[((size_t)p * NN + m) * 4 + c]
                               : l1[((size_t)(j - 1) * 16 + c) * NN + m];
            float b = (j < 4) ? l1[((size_t)j * 16 + c) * NN + m]
                              : l2[((size_t)3 * 16 + c) * NN + m];  // t16
            v = fabsf(a - b);
        } else {
            int gg = f - 18, j2, uc;
            if (gg < 3)       { j2 = 1; uc = gg; }
            else if (gg < 9)  { j2 = 2; uc = gg - 3; }
            else if (gg < 18) { j2 = 3; uc = gg - 9; }
            else              { j2 = 4; uc = gg - 18; }
            v = fabsf(l2[((size_t)(j2 - 1) * 16 + uc + 4) * NN + m]
                    - l2[((size_t)j2 * 16 + uc + 4) * NN + m]);
        }
        s += v;
    }
#pragma unroll
    for (int off = 32; off > 0; off >>= 1) s += __shfl_down(s, off, 64);
    if (lane == 0) out[p * 48 + f] = s * (1.0f / NN);
}

extern "C" void kernel_launch(void* const* d_in, const int* in_sizes, int n_in,
                              void* d_out, int out_size, void* d_ws, size_t ws_size,
                              hipStream_t stream) {
    const float* pc     = (const float*)d_in[0];
    const float* alphas = (const float*)d_in[1];
    float* outp = (float*)d_out;

    char* base = (char*)d_ws;
    size_t off = 0;
    auto carve = [&](size_t bytes) -> void* {
        void* r = base + off;
        off = (off + bytes + 255) & ~(size_t)255;
        return r;
    };
    float*     Xs  = (float*)carve((size_t)NPAIR * NN * 4 * sizeof(float));
    _Float16*  Xp  = (_Float16*)carve((size_t)NPAIR * 1024 * 8 * 2);
    float*     ihd = (float*)carve((size_t)NPAIR * NN * sizeof(float));
    _Float16*  XT  = (_Float16*)carve((size_t)NPAIR * 16 * NN * 2);
    _Float16*  pA  = (_Float16*)carve((size_t)NPAIR * 16 * NN * 2);
    _Float16*  pB  = (_Float16*)carve((size_t)NPAIR * 16 * NN * 2);
    float*     LT1 = (float*)carve((size_t)NPAIR * 5 * 16 * NN * sizeof(float));
    float*     LT2 = (float*)carve((size_t)NPAIR * 5 * 16 * NN * sizeof(float));

    dim3 gridA(NN / 32, NPAIR);   // 64 x 16 = 1024 blocks

    initpack_k<<<dim3((NPAIR * NN) / 256), 256, 0, stream>>>(pc, alphas, Xs, XT, Xp);

    // phase 1: bank1 steps 1..8 (t=1,2,4,8 -> LT1 slots 0..3); step 8 also
    // packs U into rows 4-15 of its output (combined bank).
    const _Float16* c1 = XT;
    int slot = 0;
    for (int step = 1; step <= 8; ++step) {
        _Float16* o1 = (c1 == pA) ? pB : pA;
        bool sv = (step & (step - 1)) == 0;
        float* lv = sv ? LT1 : nullptr;
        if (step == 1)
            apply_k<true, false><<<gridA, 512, 0, stream>>>(Xs, Xp, ihd,
                c1, o1, lv, slot, nullptr);
        else if (step == 8)
            apply_k<false, true><<<gridA, 512, 0, stream>>>(Xs, Xp, ihd,
                c1, o1, lv, slot, LT1);
        else
            apply_k<false, false><<<gridA, 512, 0, stream>>>(Xs, Xp, ihd,
                c1, o1, lv, slot, nullptr);
        if (sv) ++slot;
        c1 = o1;
    }

    // phase 2: combined bank, 16 uniform steps.
    // saves at i = 1,2,4,8,16 -> LT2 slots 0..4 (slot 3 rows 0-2 double as
    // bank1 t=16 low-pass; rows 4-15 are the diffused-U chain).
    int slot2 = 0;
    for (int i = 1; i <= 16; ++i) {
        _Float16* o1 = (c1 == pA) ? pB : pA;
        bool sv = (i & (i - 1)) == 0;
        float* lv = sv ? LT2 : nullptr;
        apply_k<false, false><<<gridA, 512, 0, stream>>>(Xs, Xp, ihd,
            c1, o1, lv, slot2, nullptr);
        if (sv) ++slot2;
        c1 = o1;
    }

    reduce_k<<<dim3(48, NPAIR), 64, 0, stream>>>(Xs, LT1, LT2, outp);
}

// Round 5
// 428.149 us; speedup vs baseline: 1.9371x; 1.0201x over previous
//
#include <hip/hip_runtime.h>
#include <hip/hip_bf16.h>

// PointCloudNetPersistencePrediction — round 24: fuse reduce_k into the last
// apply. R23 (barrier removal) was neutral -> per-apply cost is eval-issue
// floor + LAUNCH BOUNDARY (~6-9us drain+dispatch+refill, per R18's -70us/8
// launches measurement). 24 sequential applies are the algorithmic critical
// path; the only removable boundary is reduce_k's. The last apply (phase-2
// i=16) has LT2-slot4 values in registers and all other feature operands
// (LT1 0-3, LT2 0-3, Xs) already in global -> its epilogue stashes slot4
// rows 4-15 to LDS and 384 thr/block (8/feature) atomicAdd per-block
// feature partials into out. d_out zeroed by initpack (no extra dispatch,
// replay-safe). Last apply's out-store + lvl-slot4-store dropped (dead).
// Inner eval loop untouched (R21/R22 lesson: operands must be LDS/register).

#define NN 2048
#define NPAIR 16

typedef _Float16 half8 __attribute__((ext_vector_type(8)));
typedef _Float16 f16x2 __attribute__((ext_vector_type(2)));
typedef float f32x4 __attribute__((ext_vector_type(4)));

extern "C" __device__ f16x2 __ocml_exp2_2f16(f16x2);   // packed v_exp_f16

#define C2F 0.28853900817779268f   //  0.2 * log2(e)
#define CWF -0.14426950408889634f  // -0.1 * log2(e)
#define NL2T 3.3219280948873623f   // -log2(0.1); qi' = qi + NL2T

// ---- init+pack fused: Xs fp32 [p][i][{x,y,z,q}]; XT fp16 [p][16][2048]
//      (row3 = ones -> deg via MFMA); Xp packed fp16 j-pair entries.
//      Also zeroes d_out (768 floats) for the fused-reduce atomics. ----
__global__ __launch_bounds__(256) void initpack_k(const float* __restrict__ pc,
                                                  const float* __restrict__ alphas,
                                                  float* __restrict__ Xs,
                                                  _Float16* __restrict__ XT,
                                                  _Float16* __restrict__ Xp,
                                                  float* __restrict__ outz) {
    int gid = blockIdx.x * 256 + threadIdx.x;
    if (gid >= NPAIR * NN) return;
    if (gid < NPAIR * 48) outz[gid] = 0.f;
    int p = gid >> 11, i = gid & (NN - 1);
    int b = p >> 2, k = p & 3;
    const float* pcr = pc + ((size_t)b * NN + i) * 3;
    const float* al  = alphas + k * 3;
    float x = pcr[0] * al[0], y = pcr[1] * al[1], z = pcr[2] * al[2];
    float q = CWF * (x * x + y * y + z * z);
    float4 o; o.x = x; o.y = y; o.z = z; o.w = q;
    ((float4*)Xs)[gid] = o;
    _Float16* xt = XT + (size_t)p * 16 * NN + i;
    xt[0 * NN] = (_Float16)x;
    xt[1 * NN] = (_Float16)y;
    xt[2 * NN] = (_Float16)z;
    xt[3 * NN] = (_Float16)1.0f;
#pragma unroll
    for (int n = 4; n < 16; ++n) xt[n * NN] = (_Float16)0.f;
    _Float16* xp = Xp + ((size_t)p * 1024 + (i >> 1)) * 8 + (i & 1);
    xp[0] = (_Float16)x; xp[2] = (_Float16)y;
    xp[4] = (_Float16)z; xp[6] = (_Float16)q;
}

// ---- fused apply: out = f16(0.5*cur + ihd (x) (W@cur^T)^T).
// 512 thr = 8 K-waves (chunk 256); lane: s=2 m-subtiles; M=32; grid (64,16).
// BUILDU: step-8 epilogue emits U into rows 4-15 of out (combined bank).
// FUSEDRED: last apply — skip out/lvl stores, stash slot4 rows 4-15 in LDS,
// 384 thr compute per-block partials of the 48 features, atomicAdd to fout.
template<bool FIRST, bool BUILDU, bool FUSEDRED>
__global__ __launch_bounds__(512, 8)
void apply_k(const float* __restrict__ Xs, const _Float16* __restrict__ Xp,
             float* __restrict__ ihd,
             const _Float16* __restrict__ cur, _Float16* __restrict__ out,
             float* __restrict__ lvl, int t,
             const float* __restrict__ LT1u, const float* __restrict__ LT2r,
             float* __restrict__ fout) {
    // [0..4095]   : staged Xp (1024 float4 entries)
    // [4096..8191]: 8 waves x 512 MFMA partials
    // [8192..8575]: BUILDU stash (3x32) / FUSEDRED slot4 stash (12x32)
    __shared__ __align__(16) float smem[8576];
    const int tid  = threadIdx.x;
    const int lane = tid & 63;
    const int wv   = tid >> 6;                     // K-group 0..7
    const int p    = blockIdx.y;
    const int m0   = blockIdx.x * 32;
    const int idx16 = lane & 15, quad = lane >> 4;

    {
        // per-wave slice staging: wave wv reads only entries
        // [wv*128, wv*128+128) in the k-loop -> stage own slice, no barrier.
        const float4* src = (const float4*)(Xp + (size_t)p * 8192);
        float4* dst = (float4*)smem;
        dst[wv * 128 + lane]      = src[wv * 128 + lane];
        dst[wv * 128 + 64 + lane] = src[wv * 128 + 64 + lane];
    }

    f16x2 qi2[2], xx2[2], xy2[2], xz2[2];
#pragma unroll
    for (int s = 0; s < 2; ++s) {
        float4 v = *(const float4*)(Xs + ((size_t)p * NN + m0 + s * 16 + idx16) * 4);
        _Float16 q = (_Float16)(v.w + NL2T);
        _Float16 x = (_Float16)(C2F * v.x);
        _Float16 y = (_Float16)(C2F * v.y);
        _Float16 z = (_Float16)(C2F * v.z);
        qi2[s] = (f16x2){q, q}; xx2[s] = (f16x2){x, x};
        xy2[s] = (f16x2){y, y}; xz2[s] = (f16x2){z, z};
    }
    const f16x2 SC2 = (f16x2){(_Float16)32768.f, (_Float16)32768.f};

    const _Float16* bp = cur + ((size_t)p * 16 + idx16) * NN + wv * 256 + quad * 8;
    f32x4 acc[2] = {{0.f,0.f,0.f,0.f},{0.f,0.f,0.f,0.f}};

    for (int kc = 0; kc < 8; ++kc) {
        const int pb = wv * 128 + kc * 16 + quad * 4;  // j-pair entry base
        half8 bf = *(const half8*)(bp + kc * 32);
        union { f16x2 h2[4]; half8 h8; } af[2];
#pragma unroll
        for (int jp = 0; jp < 4; ++jp) {
            union { float4 f; f16x2 h[4]; } e;
            e.f = ((const float4*)smem)[pb + jp];      // {x2,y2,z2,q2} for 2 j
#pragma unroll
            for (int s = 0; s < 2; ++s) {
                f16x2 tv = qi2[s] + e.h[3];
                tv = __builtin_elementwise_fma(xx2[s], e.h[0], tv);
                tv = __builtin_elementwise_fma(xy2[s], e.h[1], tv);
                tv = __builtin_elementwise_fma(xz2[s], e.h[2], tv);
                // threshold folded into exp arg: t'<0 -> arg<=-24 -> exp2 = 0
                f16x2 u = __builtin_elementwise_min(tv, tv * SC2);
                af[s].h2[jp] = __ocml_exp2_2f16(u);    // = 10*w (2^3.32 fold)
            }
        }
#pragma unroll
        for (int s = 0; s < 2; ++s)
            acc[s] = __builtin_amdgcn_mfma_f32_16x16x32_f16(af[s].h8, bf, acc[s], 0, 0, 0);
    }

    // ---- epilogue (coalesced mapping: n = tid>>5, row = m0 + (tid&31)) ----
    const int n  = tid >> 5;                        // output row of [16][NN]
    const int rr = tid & 31;                        // row within m-block
    const int s2 = rr >> 4, mloc = rr & 15;
    const int base = s2 * 256 + (mloc >> 2) * 64 + (mloc & 3);
    const int row = m0 + rr;
    float ihEff;
    if (!FIRST) ihEff = 0.1f * ihd[p * NN + row];

#pragma unroll
    for (int s = 0; s < 2; ++s)
        *(f32x4*)&smem[4096 + wv * 512 + s * 256 + lane * 4] = acc[s];
    __syncthreads();

    float sum = 0.f;                               // = 10*(W@B)
#pragma unroll
    for (int g = 0; g < 8; ++g) sum += smem[4096 + g * 512 + base + n * 4];
    if (FIRST) {
        float deg10 = 0.f;                         // = 10*deg (col 3 = ones)
#pragma unroll
        for (int g = 0; g < 8; ++g) deg10 += smem[4096 + g * 512 + base + 12];
        float ih = 5.0f / deg10;                   // = 0.5/deg
        if (n == 3) ihd[p * NN + row] = ih;
        ihEff = 0.1f * ih;
    }
    float cv = (float)cur[((size_t)p * 16 + n) * NN + row];
    float o1v = 0.5f * cv + ihEff * sum;
    if (lvl) lvl[(((size_t)p * 5 + t) * 16 + n) * NN + row] = o1v;

    if (FUSEDRED) {
        // ---- fused final reduction: this launch IS LT2 slot 4 ----
        if (n >= 4) smem[8192 + (n - 4) * 32 + rr] = o1v;   // slot4 rows 4-15
        __syncthreads();
        if (tid < 384) {
            const int f = tid >> 3, g = tid & 7;            // 48 f x 8 thr
            const float* l1 = LT1u + (size_t)p * 5 * 16 * NN;
            const float* l2 = LT2r + (size_t)p * 5 * 16 * NN;
            float s = 0.f;
#pragma unroll
            for (int k = 0; k < 4; ++k) {
                const int m = m0 + g * 4 + k;
                float v;
                if (f < 3) {
                    v = l2[((size_t)3 * 16 + f) * NN + m];  // P^16 F (slot3 r0-2)
                } else if (f < 18) {
                    int j = (f - 3) / 3, c = (f - 3) % 3;
                    float a = (j == 0) ? Xs[((size_t)p * NN + m) * 4 + c]
                                       : l1[((size_t)(j - 1) * 16 + c) * NN + m];
                    float b = (j < 4) ? l1[((size_t)j * 16 + c) * NN + m]
                                      : l2[((size_t)3 * 16 + c) * NN + m];
                    v = fabsf(a - b);
                } else {
                    int gg = f - 18, j2, uc;
                    if (gg < 3)       { j2 = 1; uc = gg; }
                    else if (gg < 9)  { j2 = 2; uc = gg - 3; }
                    else if (gg < 18) { j2 = 3; uc = gg - 9; }
                    else              { j2 = 4; uc = gg - 18; }
                    float a = l2[((size_t)(j2 - 1) * 16 + uc + 4) * NN + m];
                    float b = (j2 == 4) ? smem[8192 + uc * 32 + (g * 4 + k)]
                                        : l2[((size_t)j2 * 16 + uc + 4) * NN + m];
                    v = fabsf(a - b);
                }
                s += v;
            }
#pragma unroll
            for (int off = 4; off > 0; off >>= 1) s += __shfl_down(s, off, 8);
            if (g == 0) atomicAdd(&fout[p * 48 + f], s * (1.0f / NN));
        }
        return;
    }

    if (!BUILDU) {
        out[((size_t)p * 16 + n) * NN + row] = (_Float16)o1v;
    } else {
        // stash fresh t=8 (rows 0-2), then overwrite rows 4-15 with U
        if (n < 3) smem[8192 + n * 32 + rr] = o1v;
        __syncthreads();
        float oval = o1v;                          // rows 0-3: t=8 state
        if (n >= 4) {                              // rows 4-15: U = |psi_jw|_c
            const int u = n - 4, jw = u / 3, c = u - 3 * jw;
            float a = (jw == 0) ? Xs[((size_t)p * NN + row) * 4 + c]
                                : LT1u[(((size_t)p * 5 + (jw - 1)) * 16 + c) * NN + row];
            float bb = (jw == 3) ? smem[8192 + c * 32 + rr]
                                 : LT1u[(((size_t)p * 5 + jw) * 16 + c) * NN + row];
            oval = fabsf(a - bb);
        }
        out[((size_t)p * 16 + n) * NN + row] = (_Float16)oval;
    }
}

extern "C" void kernel_launch(void* const* d_in, const int* in_sizes, int n_in,
                              void* d_out, int out_size, void* d_ws, size_t ws_size,
                              hipStream_t stream) {
    const float* pc     = (const float*)d_in[0];
    const float* alphas = (const float*)d_in[1];
    float* outp = (float*)d_out;

    char* base = (char*)d_ws;
    size_t off = 0;
    auto carve = [&](size_t bytes) -> void* {
        void* r = base + off;
        off = (off + bytes + 255) & ~(size_t)255;
        return r;
    };
    float*     Xs  = (float*)carve((size_t)NPAIR * NN * 4 * sizeof(float));
    _Float16*  Xp  = (_Float16*)carve((size_t)NPAIR * 1024 * 8 * 2);
    float*     ihd = (float*)carve((size_t)NPAIR * NN * sizeof(float));
    _Float16*  XT  = (_Float16*)carve((size_t)NPAIR * 16 * NN * 2);
    _Float16*  pA  = (_Float16*)carve((size_t)NPAIR * 16 * NN * 2);
    _Float16*  pB  = (_Float16*)carve((size_t)NPAIR * 16 * NN * 2);
    float*     LT1 = (float*)carve((size_t)NPAIR * 5 * 16 * NN * sizeof(float));
    float*     LT2 = (float*)carve((size_t)NPAIR * 5 * 16 * NN * sizeof(float));

    dim3 gridA(NN / 32, NPAIR);   // 64 x 16 = 1024 blocks

    initpack_k<<<dim3((NPAIR * NN) / 256), 256, 0, stream>>>(pc, alphas, Xs, XT, Xp, outp);

    // phase 1: bank1 steps 1..8 (t=1,2,4,8 -> LT1 slots 0..3); step 8 also
    // packs U into rows 4-15 of its output (combined bank).
    const _Float16* c1 = XT;
    int slot = 0;
    for (int step = 1; step <= 8; ++step) {
        _Float16* o1 = (c1 == pA) ? pB : pA;
        bool sv = (step & (step - 1)) == 0;
        float* lv = sv ? LT1 : nullptr;
        if (step == 1)
            apply_k<true, false, false><<<gridA, 512, 0, stream>>>(Xs, Xp, ihd,
                c1, o1, lv, slot, nullptr, nullptr, nullptr);
        else if (step == 8)
            apply_k<false, true, false><<<gridA, 512, 0, stream>>>(Xs, Xp, ihd,
                c1, o1, lv, slot, LT1, nullptr, nullptr);
        else
            apply_k<false, false, false><<<gridA, 512, 0, stream>>>(Xs, Xp, ihd,
                c1, o1, lv, slot, nullptr, nullptr, nullptr);
        if (sv) ++slot;
        c1 = o1;
    }

    // phase 2: combined bank, 16 uniform steps.
    // saves at i = 1,2,4,8 -> LT2 slots 0..3 (slot 3 rows 0-2 double as
    // bank1 t=16 low-pass; rows 4-15 are the diffused-U chain).
    // i = 16 (slot 4) is the FUSEDRED launch: values consumed in-register,
    // no lvl/out stores, per-block feature partials atomicAdd'ed to out.
    int slot2 = 0;
    for (int i = 1; i <= 16; ++i) {
        _Float16* o1 = (c1 == pA) ? pB : pA;
        bool sv = (i & (i - 1)) == 0;
        if (i == 16) {
            apply_k<false, false, true><<<gridA, 512, 0, stream>>>(Xs, Xp, ihd,
                c1, o1, nullptr, 4, LT1, LT2, outp);
        } else {
            float* lv = sv ? LT2 : nullptr;
            apply_k<false, false, false><<<gridA, 512, 0, stream>>>(Xs, Xp, ihd,
                c1, o1, lv, slot2, nullptr, nullptr, nullptr);
            if (sv) ++slot2;
        }
        c1 = o1;
    }
}

// Round 6
// 423.278 us; speedup vs baseline: 1.9594x; 1.0115x over previous
//
#include <hip/hip_runtime.h>
#include <hip/hip_bf16.h>

// PointCloudNetPersistencePrediction — round 25: kill initpack + dead-row
// traffic. 24 launches (the algorithmic critical path: 8 bank1 + 16 U-chain).
// MODE 0 (step 1): fused init — B operand built in-register from the same
//   LDS j-pair entries the eval reads (rows 0-2 = x/y/z, row 3 = 1, rest 0;
//   bit-identical to old XT), Xp computed from pc*alphas during per-wave
//   staging (block x==0 writes global Xp), Xs written per-block, d_out
//   zeroed. XT buffer + initpack launch deleted.
// MODE 1 (steps 2-7) / 2 (step 8 BUILDU): phase-1 chain rows 0-2 only live
//   -> load B rows idx16<3 (rest zeroed in-register), store n<3. BUILDU
//   stores all 16 (row 3 = exact 0) so phase 2 starts clean.
// MODE 3 (phase-2 i=1-8): full; lvl trimmed to consumed rows (n>=4, +n<3
//   at slot 3). MODE 4 (i=9-15): rows 0-2 dead -> skip their loads/stores.
// MODE 5 (i=16): fused final reduction (R24) + skip rows 0-3 loads.
// Eval inner loop untouched (R21/R22: operands must be LDS/register).

#define NN 2048
#define NPAIR 16

typedef _Float16 half8 __attribute__((ext_vector_type(8)));
typedef _Float16 f16x2 __attribute__((ext_vector_type(2)));
typedef float f32x4 __attribute__((ext_vector_type(4)));

extern "C" __device__ f16x2 __ocml_exp2_2f16(f16x2);   // packed v_exp_f16

#define C2F 0.28853900817779268f   //  0.2 * log2(e)
#define CWF -0.14426950408889634f  // -0.1 * log2(e)
#define NL2T 3.3219280948873623f   // -log2(0.1); qi' = qi + NL2T

// MODE: 0=STEP1(fused init), 1=P1, 2=P1+BUILDU, 3=P2, 4=P2TAIL, 5=FUSEDRED
template<int MODE>
__global__ __launch_bounds__(512, 8)
void apply_k(const float* __restrict__ pc, const float* __restrict__ alphas,
             float* __restrict__ Xs, _Float16* __restrict__ Xp,
             float* __restrict__ ihd,
             const _Float16* __restrict__ cur, _Float16* __restrict__ out,
             float* __restrict__ lvl, int t,
             const float* __restrict__ LT1u, const float* __restrict__ LT2r,
             float* __restrict__ fout) {
    // [0..4095]   : staged j-pair entries (1024 float4)
    // [4096..8191]: 8 waves x 512 MFMA partials
    // [8192..8575]: BUILDU stash (3x32) / FUSEDRED slot4 stash (12x32)
    __shared__ __align__(16) float smem[8576];
    const int tid  = threadIdx.x;
    const int lane = tid & 63;
    const int wv   = tid >> 6;                     // K-group 0..7
    const int p    = blockIdx.y;
    const int m0   = blockIdx.x * 32;
    const int idx16 = lane & 15, quad = lane >> 4;
    const int b = p >> 2;

    float a0, a1, a2;
    if (MODE == 0) {
        const int kk = p & 3;
        a0 = alphas[kk * 3 + 0]; a1 = alphas[kk * 3 + 1]; a2 = alphas[kk * 3 + 2];
        if (blockIdx.x == 0 && tid < 48) fout[p * 48 + tid] = 0.f;
        // per-wave slice: compute own 128 j-pair entries from pc*alphas
        float4* dst = (float4*)smem;
#pragma unroll
        for (int e = 0; e < 2; ++e) {
            const int idx = wv * 128 + e * 64 + lane;
            const float* r = pc + ((size_t)b * NN + idx * 2) * 3;  // 2 points, 6 floats
            float x0 = r[0] * a0, y0 = r[1] * a1, z0 = r[2] * a2;
            float x1 = r[3] * a0, y1 = r[4] * a1, z1 = r[5] * a2;
            float q0 = CWF * (x0 * x0 + y0 * y0 + z0 * z0);
            float q1 = CWF * (x1 * x1 + y1 * y1 + z1 * z1);
            union { float4 f; f16x2 h[4]; } ev;
            ev.h[0] = (f16x2){(_Float16)x0, (_Float16)x1};
            ev.h[1] = (f16x2){(_Float16)y0, (_Float16)y1};
            ev.h[2] = (f16x2){(_Float16)z0, (_Float16)z1};
            ev.h[3] = (f16x2){(_Float16)q0, (_Float16)q1};
            dst[idx] = ev.f;
            if (blockIdx.x == 0) ((float4*)Xp)[(size_t)p * 1024 + idx] = ev.f;
        }
    } else {
        // per-wave slice staging from global Xp (no barrier needed)
        const float4* src = (const float4*)(Xp + (size_t)p * 8192);
        float4* dst = (float4*)smem;
        dst[wv * 128 + lane]      = src[wv * 128 + lane];
        dst[wv * 128 + 64 + lane] = src[wv * 128 + 64 + lane];
    }

    f16x2 qi2[2], xx2[2], xy2[2], xz2[2];
#pragma unroll
    for (int s = 0; s < 2; ++s) {
        const int row = m0 + s * 16 + idx16;
        float fx, fy, fz, fq;
        if (MODE == 0) {
            const float* r = pc + ((size_t)b * NN + row) * 3;
            fx = r[0] * a0; fy = r[1] * a1; fz = r[2] * a2;
            fq = CWF * (fx * fx + fy * fy + fz * fz);
            if (wv == 0 && quad == 0) {
                float4 o; o.x = fx; o.y = fy; o.z = fz; o.w = fq;
                *(float4*)(Xs + ((size_t)p * NN + row) * 4) = o;
            }
        } else {
            float4 v = *(const float4*)(Xs + ((size_t)p * NN + row) * 4);
            fx = v.x; fy = v.y; fz = v.z; fq = v.w;
        }
        _Float16 q = (_Float16)(fq + NL2T);
        _Float16 x = (_Float16)(C2F * fx);
        _Float16 y = (_Float16)(C2F * fy);
        _Float16 z = (_Float16)(C2F * fz);
        qi2[s] = (f16x2){q, q}; xx2[s] = (f16x2){x, x};
        xy2[s] = (f16x2){y, y}; xz2[s] = (f16x2){z, z};
    }
    const f16x2 SC2 = (f16x2){(_Float16)32768.f, (_Float16)32768.f};
    const f16x2 ONE2 = (f16x2){(_Float16)1.f, (_Float16)1.f};
    const f16x2 ZER2 = (f16x2){(_Float16)0.f, (_Float16)0.f};

    const _Float16* bp = cur + ((size_t)p * 16 + idx16) * NN + wv * 256 + quad * 8;
    f32x4 acc[2] = {{0.f,0.f,0.f,0.f},{0.f,0.f,0.f,0.f}};

    for (int kc = 0; kc < 8; ++kc) {
        const int pb = wv * 128 + kc * 16 + quad * 4;  // j-pair entry base
        union { f16x2 h2[4]; half8 h8; } bfu;
        if (MODE != 0) {
            bool ld;
            if (MODE == 3)                 ld = true;
            else if (MODE == 1 || MODE == 2) ld = (idx16 < 3);
            else if (MODE == 4)            ld = (idx16 >= 3);
            else                           ld = (idx16 >= 4);
            if (ld) bfu.h8 = *(const half8*)(bp + kc * 32);
            else {
#pragma unroll
                for (int z = 0; z < 4; ++z) bfu.h2[z] = ZER2;
            }
        }
        union { f16x2 h2[4]; half8 h8; } af[2];
#pragma unroll
        for (int jp = 0; jp < 4; ++jp) {
            union { float4 f; f16x2 h[4]; } e;
            e.f = ((const float4*)smem)[pb + jp];      // {x2,y2,z2,q2} for 2 j
            if (MODE == 0) {                           // B = {x,y,z,1,0..} in-reg
                bfu.h2[jp] = (idx16 == 0) ? e.h[0]
                           : (idx16 == 1) ? e.h[1]
                           : (idx16 == 2) ? e.h[2]
                           : (idx16 == 3) ? ONE2 : ZER2;
            }
#pragma unroll
            for (int s = 0; s < 2; ++s) {
                f16x2 tv = qi2[s] + e.h[3];
                tv = __builtin_elementwise_fma(xx2[s], e.h[0], tv);
                tv = __builtin_elementwise_fma(xy2[s], e.h[1], tv);
                tv = __builtin_elementwise_fma(xz2[s], e.h[2], tv);
                // threshold folded into exp arg: t'<0 -> arg<=-24 -> exp2 = 0
                f16x2 u = __builtin_elementwise_min(tv, tv * SC2);
                af[s].h2[jp] = __ocml_exp2_2f16(u);    // = 10*w (2^3.32 fold)
            }
        }
#pragma unroll
        for (int s = 0; s < 2; ++s)
            acc[s] = __builtin_amdgcn_mfma_f32_16x16x32_f16(af[s].h8, bfu.h8, acc[s], 0, 0, 0);
    }

    // ---- epilogue (coalesced mapping: n = tid>>5, row = m0 + (tid&31)) ----
    const int n  = tid >> 5;                        // output row of [16][NN]
    const int rr = tid & 31;                        // row within m-block
    const int s2 = rr >> 4, mloc = rr & 15;
    const int base = s2 * 256 + (mloc >> 2) * 64 + (mloc & 3);
    const int row = m0 + rr;
    float ihEff;
    if (MODE != 0) ihEff = 0.1f * ihd[p * NN + row];

#pragma unroll
    for (int s = 0; s < 2; ++s)
        *(f32x4*)&smem[4096 + wv * 512 + s * 256 + lane * 4] = acc[s];
    __syncthreads();

    float sum = 0.f;                               // = 10*(W@B)
#pragma unroll
    for (int g = 0; g < 8; ++g) sum += smem[4096 + g * 512 + base + n * 4];
    if (MODE == 0) {
        float deg10 = 0.f;                         // = 10*deg (col 3 = ones)
#pragma unroll
        for (int g = 0; g < 8; ++g) deg10 += smem[4096 + g * 512 + base + 12];
        float ih = 5.0f / deg10;                   // = 0.5/deg
        if (n == 3) ihd[p * NN + row] = ih;
        ihEff = 0.1f * ih;
    }
    float cv;
    if (MODE == 0) {
        cv = (n < 3) ? pc[((size_t)b * NN + row) * 3 + n] * alphas[(p & 3) * 3 + n] : 0.f;
    } else if (MODE == 1 || MODE == 2) {
        cv = (n < 3) ? (float)cur[((size_t)p * 16 + n) * NN + row] : 0.f;
    } else if (MODE == 3) {
        cv = (float)cur[((size_t)p * 16 + n) * NN + row];
    } else {                                       // 4, 5
        cv = (n >= 4) ? (float)cur[((size_t)p * 16 + n) * NN + row] : 0.f;
    }
    float o1v = 0.5f * cv + ihEff * sum;

    if (MODE == 0 || MODE == 1) {
        if (n < 3) {
            out[((size_t)p * 16 + n) * NN + row] = (_Float16)o1v;
            if (lvl) lvl[(((size_t)p * 5 + t) * 16 + n) * NN + row] = o1v;
        }
    } else if (MODE == 2) {
        // stash fresh t=8 (rows 0-2), then emit combined bank (row 3 = 0)
        if (n < 3) {
            lvl[(((size_t)p * 5 + t) * 16 + n) * NN + row] = o1v;
            smem[8192 + n * 32 + rr] = o1v;
        }
        __syncthreads();
        float oval = o1v;                          // n<3: t8; n==3: exact 0
        if (n >= 4) {                              // rows 4-15: U = |psi_jw|_c
            const int u = n - 4, jw = u / 3, c = u - 3 * jw;
            float a = (jw == 0) ? Xs[((size_t)p * NN + row) * 4 + c]
                                : LT1u[(((size_t)p * 5 + (jw - 1)) * 16 + c) * NN + row];
            float bb = (jw == 3) ? smem[8192 + c * 32 + rr]
                                 : LT1u[(((size_t)p * 5 + jw) * 16 + c) * NN + row];
            oval = fabsf(a - bb);
        }
        out[((size_t)p * 16 + n) * NN + row] = (_Float16)oval;
    } else if (MODE == 3) {
        out[((size_t)p * 16 + n) * NN + row] = (_Float16)o1v;
        if (lvl && (n >= 4 || (t == 3 && n < 3)))
            lvl[(((size_t)p * 5 + t) * 16 + n) * NN + row] = o1v;
    } else if (MODE == 4) {
        if (n >= 4) out[((size_t)p * 16 + n) * NN + row] = (_Float16)o1v;
    } else {                                       // MODE 5: fused reduction
        if (n >= 4) smem[8192 + (n - 4) * 32 + rr] = o1v;   // slot4 rows 4-15
        __syncthreads();
        if (tid < 384) {
            const int f = tid >> 3, g = tid & 7;            // 48 f x 8 thr
            const float* l1 = LT1u + (size_t)p * 5 * 16 * NN;
            const float* l2 = LT2r + (size_t)p * 5 * 16 * NN;
            float s = 0.f;
#pragma unroll
            for (int k = 0; k < 4; ++k) {
                const int m = m0 + g * 4 + k;
                float v;
                if (f < 3) {
                    v = l2[((size_t)3 * 16 + f) * NN + m];  // P^16 F (slot3 r0-2)
                } else if (f < 18) {
                    int j = (f - 3) / 3, c = (f - 3) % 3;
                    float a = (j == 0) ? Xs[((size_t)p * NN + m) * 4 + c]
                                       : l1[((size_t)(j - 1) * 16 + c) * NN + m];
                    float bb = (j < 4) ? l1[((size_t)j * 16 + c) * NN + m]
                                       : l2[((size_t)3 * 16 + c) * NN + m];
                    v = fabsf(a - bb);
                } else {
                    int gg = f - 18, j2, uc;
                    if (gg < 3)       { j2 = 1; uc = gg; }
                    else if (gg < 9)  { j2 = 2; uc = gg - 3; }
                    else if (gg < 18) { j2 = 3; uc = gg - 9; }
                    else              { j2 = 4; uc = gg - 18; }
                    float a = l2[((size_t)(j2 - 1) * 16 + uc + 4) * NN + m];
                    float bb = (j2 == 4) ? smem[8192 + uc * 32 + (g * 4 + k)]
                                         : l2[((size_t)j2 * 16 + uc + 4) * NN + m];
                    v = fabsf(a - bb);
                }
                s += v;
            }
#pragma unroll
            for (int off = 4; off > 0; off >>= 1) s += __shfl_down(s, off, 8);
            if (g == 0) atomicAdd(&fout[p * 48 + f], s * (1.0f / NN));
        }
    }
}

extern "C" void kernel_launch(void* const* d_in, const int* in_sizes, int n_in,
                              void* d_out, int out_size, void* d_ws, size_t ws_size,
                              hipStream_t stream) {
    const float* pc     = (const float*)d_in[0];
    const float* alphas = (const float*)d_in[1];
    float* outp = (float*)d_out;

    char* base = (char*)d_ws;
    size_t off = 0;
    auto carve = [&](size_t bytes) -> void* {
        void* r = base + off;
        off = (off + bytes + 255) & ~(size_t)255;
        return r;
    };
    float*     Xs  = (float*)carve((size_t)NPAIR * NN * 4 * sizeof(float));
    _Float16*  Xp  = (_Float16*)carve((size_t)NPAIR * 1024 * 8 * 2);
    float*     ihd = (float*)carve((size_t)NPAIR * NN * sizeof(float));
    _Float16*  pA  = (_Float16*)carve((size_t)NPAIR * 16 * NN * 2);
    _Float16*  pB  = (_Float16*)carve((size_t)NPAIR * 16 * NN * 2);
    float*     LT1 = (float*)carve((size_t)NPAIR * 5 * 16 * NN * sizeof(float));
    float*     LT2 = (float*)carve((size_t)NPAIR * 5 * 16 * NN * sizeof(float));

    dim3 gridA(NN / 32, NPAIR);   // 64 x 16 = 1024 blocks

    // step 1: fused init (Xs/Xp/out-zero) + apply (t=1 -> LT1 slot 0, ihd)
    apply_k<0><<<gridA, 512, 0, stream>>>(pc, alphas, Xs, Xp, ihd,
        nullptr, pA, LT1, 0, nullptr, nullptr, outp);
    const _Float16* c1 = pA;
    int slot = 1;

    // phase 1: bank1 steps 2..8 (t=2,4,8 -> LT1 slots 1..3); step 8 packs U
    // into rows 4-15 of its output (combined bank, row 3 = 0).
    for (int step = 2; step <= 8; ++step) {
        _Float16* o1 = (c1 == pA) ? pB : pA;
        bool sv = (step & (step - 1)) == 0;
        if (step == 8)
            apply_k<2><<<gridA, 512, 0, stream>>>(pc, alphas, Xs, Xp, ihd,
                c1, o1, LT1, 3, LT1, nullptr, nullptr);
        else
            apply_k<1><<<gridA, 512, 0, stream>>>(pc, alphas, Xs, Xp, ihd,
                c1, o1, sv ? LT1 : nullptr, slot, nullptr, nullptr, nullptr);
        if (sv) ++slot;
        c1 = o1;
    }

    // phase 2: combined bank, 16 steps. saves i=1,2,4,8 -> LT2 slots 0..3
    // (slot 3 rows 0-2 = bank1 t16 low-pass). i=9..15: rows 0-2 dead ->
    // trimmed. i=16: fused final reduction (atomicAdd into d_out).
    int slot2 = 0;
    for (int i = 1; i <= 16; ++i) {
        _Float16* o1 = (c1 == pA) ? pB : pA;
        if (i == 16) {
            apply_k<5><<<gridA, 512, 0, stream>>>(pc, alphas, Xs, Xp, ihd,
                c1, o1, nullptr, 4, LT1, LT2, outp);
        } else if (i <= 8) {
            bool sv = (i & (i - 1)) == 0;
            apply_k<3><<<gridA, 512, 0, stream>>>(pc, alphas, Xs, Xp, ihd,
                c1, o1, sv ? LT2 : nullptr, slot2, nullptr, nullptr, nullptr);
            if (sv) ++slot2;
        } else {
            apply_k<4><<<gridA, 512, 0, stream>>>(pc, alphas, Xs, Xp, ihd,
                c1, o1, nullptr, 0, nullptr, nullptr, nullptr);
        }
        c1 = o1;
    }
}